// Round 1
// baseline (3117.703 us; speedup 1.0000x reference)
//
#include <hip/hip_runtime.h>
#include <math.h>

#define N0 8192
#define D 128

// ---------------- score: s[i] = tanh((x[i]·w)/||w||), tanh in fp64 ----------------
__global__ void score_kernel(const float* __restrict__ x, const float* __restrict__ w,
                             float* __restrict__ score, int n) {
    __shared__ float red[128];
    __shared__ float red2[128];
    int row = blockIdx.x;
    int t = threadIdx.x;
    float wv = w[t];
    float xv = x[row * D + t];
    red[t] = xv * wv;
    red2[t] = wv * wv;
    __syncthreads();
    for (int s = 64; s > 0; s >>= 1) {
        if (t < s) { red[t] += red[t + s]; red2[t] += red2[t + s]; }
        __syncthreads();
    }
    if (t == 0) {
        double a = (double)red[0] / sqrt((double)red2[0]);
        score[row] = (float)tanh(a);
    }
}

// ---------------- exact top-k: bitonic sort of (desc score, asc index) keys -------
__global__ void topk_sort_kernel(const float* __restrict__ score, int n, int k,
                                 int* __restrict__ perm, float* __restrict__ gate) {
    extern __shared__ unsigned long long keys[];
    int t = threadIdx.x;
    int bs = blockDim.x;
    for (int i = t; i < n; i += bs) {
        unsigned int b = __float_as_uint(score[i]);
        unsigned int ord = (b & 0x80000000u) ? ~b : (b | 0x80000000u); // ascending float order
        unsigned int inv = ~ord;                                       // ascending == descending float
        keys[i] = ((unsigned long long)inv << 32) | (unsigned int)i;
    }
    __syncthreads();
    for (int len = 2; len <= n; len <<= 1) {
        for (int str = len >> 1; str > 0; str >>= 1) {
            for (int i = t; i < n; i += bs) {
                int j = i ^ str;
                if (j > i) {
                    unsigned long long a = keys[i], c = keys[j];
                    bool up = ((i & len) == 0);
                    if ((a > c) == up) { keys[i] = c; keys[j] = a; }
                }
            }
            __syncthreads();
        }
    }
    for (int i = t; i < k; i += bs) {
        int idx = (int)(keys[i] & 0xffffffffu);
        perm[i] = idx;
        gate[i] = score[idx];
    }
}

// ---------------- xp[j] = x[perm[j]] * gate[j] ----------------
__global__ void pool_gather_kernel(const float* __restrict__ x, const int* __restrict__ perm,
                                   const float* __restrict__ gate, float* __restrict__ xp, int k) {
    int idx = blockIdx.x * blockDim.x + threadIdx.x;
    if (idx >= k * D) return;
    int j = idx >> 7;
    int d = idx & 127;
    xp[idx] = x[perm[j] * D + d] * gate[j];
}

// ---------------- Hg[r][c] = H[perm[r]][perm[c]] (full H, row stride N0) ----------
__global__ void h_gather_kernel(const float* __restrict__ H, const int* __restrict__ perm,
                                float* __restrict__ Hg, int k, int lg) {
    int idx = blockIdx.x * blockDim.x + threadIdx.x;
    int r = idx >> lg;
    int c = idx & (k - 1);
    if (r >= k) return;
    Hg[idx] = H[perm[r] * N0 + perm[c]];
}

// ---------------- T = X @ W + b   (X: n x 128, W: 128 x 128) ----------------
__global__ __launch_bounds__(256) void gemm_xw_kernel(const float* __restrict__ X,
                                                      const float* __restrict__ W,
                                                      const float* __restrict__ bias,
                                                      float* __restrict__ T, int n) {
    __shared__ float Xs[64][33];
    __shared__ float Ws[32][128];
    int tid = threadIdx.x;
    int bm = blockIdx.x;
    int tx = tid & 15;   // 16 col groups * 8 cols
    int ty = tid >> 4;   // 16 row groups * 4 rows
    float acc[4][8];
#pragma unroll
    for (int i = 0; i < 4; i++)
#pragma unroll
        for (int j = 0; j < 8; j++) acc[i][j] = 0.f;

    for (int k0 = 0; k0 < 128; k0 += 32) {
        for (int l = tid; l < 64 * 32; l += 256) {
            int r = l >> 5, kk = l & 31;
            Xs[r][kk] = X[(bm * 64 + r) * 128 + k0 + kk];
        }
        for (int l = tid; l < 32 * 128; l += 256) {
            int kk = l >> 7, c = l & 127;
            Ws[kk][c] = W[(k0 + kk) * 128 + c];
        }
        __syncthreads();
#pragma unroll
        for (int kk = 0; kk < 32; ++kk) {
            float a[4], bb[8];
#pragma unroll
            for (int i = 0; i < 4; i++) a[i] = Xs[ty * 4 + i][kk];
#pragma unroll
            for (int j = 0; j < 8; j++) bb[j] = Ws[kk][tx * 8 + j];
#pragma unroll
            for (int i = 0; i < 4; i++)
#pragma unroll
                for (int j = 0; j < 8; j++) acc[i][j] += a[i] * bb[j];
        }
        __syncthreads();
    }
#pragma unroll
    for (int i = 0; i < 4; i++) {
        int row = bm * 64 + ty * 4 + i;
#pragma unroll
        for (int j = 0; j < 8; j++) {
            int col = tx * 8 + j;
            T[row * 128 + col] = acc[i][j] + bias[col];
        }
    }
}

// ---------------- C = relu(A @ B)   A: M x K (row-major), B: K x 128 ----------------
__global__ __launch_bounds__(256) void gemm_big_kernel(const float* __restrict__ A,
                                                       const float* __restrict__ B,
                                                       float* __restrict__ C, int M, int K) {
    __shared__ float As[64][33];
    __shared__ float Bs[32][64];
    int tid = threadIdx.x;
    int bm = blockIdx.x, bn = blockIdx.y;
    int tx = tid & 15;   // 16 col groups * 4
    int ty = tid >> 4;   // 16 row groups * 4
    float acc[4][4];
#pragma unroll
    for (int i = 0; i < 4; i++)
#pragma unroll
        for (int j = 0; j < 4; j++) acc[i][j] = 0.f;

    const float* Ab = A + bm * 64 * K;
    const float* Bb = B + bn * 64;
    for (int k0 = 0; k0 < K; k0 += 32) {
        for (int l = tid; l < 64 * 32; l += 256) {
            int r = l >> 5, kk = l & 31;
            As[r][kk] = Ab[r * K + k0 + kk];
        }
        for (int l = tid; l < 32 * 64; l += 256) {
            int kk = l >> 6, c = l & 63;
            Bs[kk][c] = Bb[(k0 + kk) * 128 + c];
        }
        __syncthreads();
#pragma unroll
        for (int kk = 0; kk < 32; ++kk) {
            float a[4], bb[4];
#pragma unroll
            for (int i = 0; i < 4; i++) a[i] = As[ty * 4 + i][kk];
#pragma unroll
            for (int j = 0; j < 4; j++) bb[j] = Bs[kk][tx * 4 + j];
#pragma unroll
            for (int i = 0; i < 4; i++)
#pragma unroll
                for (int j = 0; j < 4; j++) acc[i][j] += a[i] * bb[j];
        }
        __syncthreads();
    }
#pragma unroll
    for (int i = 0; i < 4; i++) {
        int row = bm * 64 + ty * 4 + i;
#pragma unroll
        for (int j = 0; j < 4; j++) {
            float v = acc[i][j];
            C[row * 128 + bn * 64 + tx * 4 + j] = v > 0.f ? v : 0.f;
        }
    }
}

// ---------------- u = src (copy) ----------------
__global__ void copy_kernel(const float* __restrict__ src, float* __restrict__ dst, int count) {
    int idx = blockIdx.x * blockDim.x + threadIdx.x;
    if (idx < count) dst[idx] = src[idx];
}

// ---------------- u[perm[j]] += xc[j] ----------------
__global__ void scatter_add_kernel(const float* __restrict__ xc, const int* __restrict__ perm,
                                   float* __restrict__ u, int k) {
    int idx = blockIdx.x * blockDim.x + threadIdx.x;
    if (idx >= k * D) return;
    int j = idx >> 7;
    int d = idx & 127;
    u[perm[j] * D + d] += xc[idx];
}

extern "C" void kernel_launch(void* const* d_in, const int* in_sizes, int n_in,
                              void* d_out, int out_size, void* d_ws, size_t ws_size,
                              hipStream_t stream) {
    const float* feat = (const float*)d_in[0];
    const float* H    = (const float*)d_in[1];
    const float* p_w[3]  = {(const float*)d_in[2], (const float*)d_in[3], (const float*)d_in[4]};
    const float* Wd[3]   = {(const float*)d_in[5], (const float*)d_in[7], (const float*)d_in[9]};
    const float* bd[3]   = {(const float*)d_in[6], (const float*)d_in[8], (const float*)d_in[10]};
    const float* Wu[3]   = {(const float*)d_in[11], (const float*)d_in[13], (const float*)d_in[15]};
    const float* bu[3]   = {(const float*)d_in[12], (const float*)d_in[14], (const float*)d_in[16]};
    float* out = (float*)d_out;

    // ---- workspace carving (floats) ----
    char* w = (char*)d_ws;
    size_t off = 0;
    auto alloc = [&](size_t nfloats) { void* p = w + off; off += nfloats * 4; return p; };
    float* Hg0 = (float*)alloc(4096ull * 4096);   // 64 MB
    float* Hg1 = (float*)alloc(2048ull * 2048);   // 16 MB
    float* Hg2 = (float*)alloc(1024ull * 1024);   //  4 MB
    float* x1  = (float*)alloc(4096ull * D);
    float* x2  = (float*)alloc(2048ull * D);
    float* xp  = (float*)alloc(4096ull * D);
    float* tbuf = (float*)alloc(8192ull * D);
    float* ubuf = (float*)alloc(8192ull * D);
    float* xc  = (float*)alloc(4096ull * D);
    float* score = (float*)alloc(8192);
    float* gate  = (float*)alloc(4096);
    int* perm0 = (int*)alloc(4096);
    int* perm1 = (int*)alloc(2048);
    int* perm2 = (int*)alloc(1024);

    const int ks[3] = {4096, 2048, 1024};
    const int ns[3] = {8192, 4096, 2048};  // node count entering each down level
    int* perms[3] = {perm0, perm1, perm2};
    float* Hgs[3] = {Hg0, Hg1, Hg2};
    const float* xin[3] = {feat, x1, x2};
    float* xout[3] = {x1, x2, xc};

    // ---------------- down path ----------------
    for (int i = 0; i < 3; i++) {
        int n = ns[i], k = ks[i];
        int lg = (k == 4096) ? 12 : (k == 2048 ? 11 : 10);
        score_kernel<<<n, 128, 0, stream>>>(xin[i], p_w[i], score, n);
        topk_sort_kernel<<<1, 1024, n * 8, stream>>>(score, n, k, perms[i], gate);
        pool_gather_kernel<<<(k * D) / 256, 256, 0, stream>>>(xin[i], perms[i], gate, xp, k);
        h_gather_kernel<<<(k * k) / 256, 256, 0, stream>>>(H, perms[i], Hgs[i], k, lg);
        gemm_xw_kernel<<<k / 64, 256, 0, stream>>>(xp, Wd[i], bd[i], tbuf, k);
        dim3 g(k / 64, 2);
        gemm_big_kernel<<<g, 256, 0, stream>>>(Hgs[i], tbuf, xout[i], k, k);
    }

    // ---------------- up path ----------------
    // i=0: j=2  res=x2(2048) graph=Hg1 perm=perm2(k=1024)
    // i=1: j=1  res=x1(4096) graph=Hg0 perm=perm1(k=2048)
    // i=2: j=0  res=feat(8192) graph=H  perm=perm0(k=4096)
    const float* res[3] = {x2, x1, feat};
    const float* graphs[3] = {Hg1, Hg0, H};
    int* uperm[3] = {perm2, perm1, perm0};
    const int un[3] = {2048, 4096, 8192};   // rows of res / graph
    const int uk[3] = {1024, 2048, 4096};   // rows of incoming x
    for (int i = 0; i < 3; i++) {
        int n = un[i], k = uk[i];
        copy_kernel<<<(n * D) / 256, 256, 0, stream>>>(res[i], ubuf, n * D);
        scatter_add_kernel<<<(k * D) / 256, 256, 0, stream>>>(xc, uperm[i], ubuf, k);
        gemm_xw_kernel<<<n / 64, 256, 0, stream>>>(ubuf, Wu[i], bu[i], tbuf, n);
        dim3 g(n / 64, 2);
        float* dst = (i == 2) ? out : xc;
        gemm_big_kernel<<<g, 256, 0, stream>>>(graphs[i], tbuf, dst, n, n);
    }
    (void)in_sizes; (void)n_in; (void)out_size; (void)ws_size;
}

// Round 2
// 1369.207 us; speedup vs baseline: 2.2770x; 2.2770x over previous
//
#include <hip/hip_runtime.h>
#include <math.h>

#define N0 8192
#define D 128

typedef __attribute__((ext_vector_type(8))) short short8;
typedef __attribute__((ext_vector_type(4))) float f32x4;

__device__ inline short f2bf(float f) {
    unsigned u = __float_as_uint(f);
    u = u + 0x7fffu + ((u >> 16) & 1u);
    return (short)(u >> 16);
}

// ---------------- score: s[i] = tanh((x[i]·w)/||w||), tanh in fp64 ----------------
__global__ void score_kernel(const float* __restrict__ x, const float* __restrict__ w,
                             float* __restrict__ score, int n) {
    __shared__ float red[128];
    __shared__ float red2[128];
    int row = blockIdx.x;
    int t = threadIdx.x;
    float wv = w[t];
    float xv = x[row * D + t];
    red[t] = xv * wv;
    red2[t] = wv * wv;
    __syncthreads();
    for (int s = 64; s > 0; s >>= 1) {
        if (t < s) { red[t] += red[t + s]; red2[t] += red2[t + s]; }
        __syncthreads();
    }
    if (t == 0) {
        double a = (double)red[0] / sqrt((double)red2[0]);
        score[row] = (float)tanh(a);
    }
}

// ---------------- exact top-k: bitonic sort of (desc score, asc index) keys -------
__global__ void topk_sort_kernel(const float* __restrict__ score, int n, int k,
                                 int* __restrict__ perm, float* __restrict__ gate) {
    extern __shared__ unsigned long long keys[];
    int t = threadIdx.x;
    int bs = blockDim.x;
    for (int i = t; i < n; i += bs) {
        unsigned int b = __float_as_uint(score[i]);
        unsigned int ord = (b & 0x80000000u) ? ~b : (b | 0x80000000u); // ascending float order
        unsigned int inv = ~ord;                                       // descending
        keys[i] = ((unsigned long long)inv << 32) | (unsigned int)i;
    }
    __syncthreads();
    for (int len = 2; len <= n; len <<= 1) {
        for (int str = len >> 1; str > 0; str >>= 1) {
            for (int i = t; i < n; i += bs) {
                int j = i ^ str;
                if (j > i) {
                    unsigned long long a = keys[i], c = keys[j];
                    bool up = ((i & len) == 0);
                    if ((a > c) == up) { keys[i] = c; keys[j] = a; }
                }
            }
            __syncthreads();
        }
    }
    for (int i = t; i < k; i += bs) {
        int idx = (int)(keys[i] & 0xffffffffu);
        perm[i] = idx;
        gate[i] = score[idx];
    }
}

// ---------------- xp[j] = x[perm[j]] * gate[j] ----------------
__global__ void pool_gather_kernel(const float* __restrict__ x, const int* __restrict__ perm,
                                   const float* __restrict__ gate, float* __restrict__ xp, int k) {
    int idx = blockIdx.x * blockDim.x + threadIdx.x;
    if (idx >= k * D) return;
    int j = idx >> 7;
    int d = idx & 127;
    xp[idx] = x[perm[j] * D + d] * gate[j];
}

// ---------------- Hg[r][c] = H[perm[r]][perm[c]] (full H, row stride N0) ----------
__global__ void h_gather_kernel(const float* __restrict__ H, const int* __restrict__ perm,
                                float* __restrict__ Hg, int k, int lg) {
    int idx = blockIdx.x * blockDim.x + threadIdx.x;
    int r = idx >> lg;
    int c = idx & (k - 1);
    if (r >= k) return;
    Hg[idx] = H[(size_t)perm[r] * N0 + perm[c]];
}

// ---------------- T = X @ W + b   (X: n x 128, W: 128 x 128) ----------------
__global__ __launch_bounds__(256) void gemm_xw_kernel(const float* __restrict__ X,
                                                      const float* __restrict__ W,
                                                      const float* __restrict__ bias,
                                                      float* __restrict__ T, int n) {
    __shared__ float Xs[64][33];
    __shared__ float Ws[32][128];
    int tid = threadIdx.x;
    int bm = blockIdx.x;
    int tx = tid & 15;   // 16 col groups * 8 cols
    int ty = tid >> 4;   // 16 row groups * 4 rows
    float acc[4][8];
#pragma unroll
    for (int i = 0; i < 4; i++)
#pragma unroll
        for (int j = 0; j < 8; j++) acc[i][j] = 0.f;

    for (int k0 = 0; k0 < 128; k0 += 32) {
        for (int l = tid; l < 64 * 32; l += 256) {
            int r = l >> 5, kk = l & 31;
            Xs[r][kk] = X[(size_t)(bm * 64 + r) * 128 + k0 + kk];
        }
        for (int l = tid; l < 32 * 128; l += 256) {
            int kk = l >> 7, c = l & 127;
            Ws[kk][c] = W[(k0 + kk) * 128 + c];
        }
        __syncthreads();
#pragma unroll
        for (int kk = 0; kk < 32; ++kk) {
            float a[4], bb[8];
#pragma unroll
            for (int i = 0; i < 4; i++) a[i] = Xs[ty * 4 + i][kk];
#pragma unroll
            for (int j = 0; j < 8; j++) bb[j] = Ws[kk][tx * 8 + j];
#pragma unroll
            for (int i = 0; i < 4; i++)
#pragma unroll
                for (int j = 0; j < 8; j++) acc[i][j] += a[i] * bb[j];
        }
        __syncthreads();
    }
#pragma unroll
    for (int i = 0; i < 4; i++) {
        int row = bm * 64 + ty * 4 + i;
#pragma unroll
        for (int j = 0; j < 8; j++) {
            int col = tx * 8 + j;
            T[(size_t)row * 128 + col] = acc[i][j] + bias[col];
        }
    }
}

// ---------------- fp32 split-K: Cacc += A(64-row strip, K-chunk) @ B ----------------
__global__ __launch_bounds__(256) void gemm_f32_kernel(const float* __restrict__ A,
                                                       const float* __restrict__ B,
                                                       float* __restrict__ Cacc,
                                                       int K, int chunk) {
    __shared__ float As[64][36];
    __shared__ float Bs[32][128];
    int tid = threadIdx.x;
    int bm = blockIdx.x;
    int tx = tid & 15;
    int ty = tid >> 4;
    float acc[4][8];
#pragma unroll
    for (int i = 0; i < 4; i++)
#pragma unroll
        for (int j = 0; j < 8; j++) acc[i][j] = 0.f;

    const float* Ab = A + (size_t)bm * 64 * K;
    int kbeg = blockIdx.y * chunk;
    for (int k0 = kbeg; k0 < kbeg + chunk; k0 += 32) {
        for (int l = tid; l < 512; l += 256) {
            int r = l >> 3, c4 = (l & 7) * 4;
            float4 v = *(const float4*)(Ab + (size_t)r * K + k0 + c4);
            As[r][c4] = v.x; As[r][c4 + 1] = v.y; As[r][c4 + 2] = v.z; As[r][c4 + 3] = v.w;
        }
        for (int l = tid; l < 1024; l += 256) {
            int r = l >> 5, c4 = (l & 31) * 4;
            *(float4*)&Bs[r][c4] = *(const float4*)(B + (size_t)(k0 + r) * 128 + c4);
        }
        __syncthreads();
#pragma unroll
        for (int kk = 0; kk < 32; ++kk) {
            float a[4];
#pragma unroll
            for (int i = 0; i < 4; i++) a[i] = As[ty * 4 + i][kk];
            float4 b0 = *(const float4*)&Bs[kk][tx * 8];
            float4 b1 = *(const float4*)&Bs[kk][tx * 8 + 4];
            float bb[8] = {b0.x, b0.y, b0.z, b0.w, b1.x, b1.y, b1.z, b1.w};
#pragma unroll
            for (int i = 0; i < 4; i++)
#pragma unroll
                for (int j = 0; j < 8; j++) acc[i][j] += a[i] * bb[j];
        }
        __syncthreads();
    }
#pragma unroll
    for (int i = 0; i < 4; i++) {
        int row = bm * 64 + ty * 4 + i;
#pragma unroll
        for (int j = 0; j < 8; j++)
            atomicAdd(&Cacc[(size_t)row * 128 + tx * 8 + j], acc[i][j]);
    }
}

// ------- transpose+convert: Tt(128 x n, bf16) = bf16(T(n x 128, fp32))^T -------
__global__ void transpose_cvt_kernel(const float* __restrict__ T, short* __restrict__ Tt, int n) {
    __shared__ float tile[32][33];
    int tx = threadIdx.x & 31, ty = threadIdx.x >> 5;   // 32 x 8
    int r0 = blockIdx.x * 32, c0 = blockIdx.y * 32;
#pragma unroll
    for (int k = 0; k < 4; k++)
        tile[ty + k * 8][tx] = T[(size_t)(r0 + ty + k * 8) * 128 + c0 + tx];
    __syncthreads();
#pragma unroll
    for (int k = 0; k < 4; k++)
        Tt[(size_t)(c0 + ty + k * 8) * n + r0 + tx] = f2bf(tile[tx][ty + k * 8]);
}

// ------- bf16 MFMA split-K: Cacc += bf16(A fp32 MxK) @ Bt^T (Bt: 128 x K bf16) -------
__global__ __launch_bounds__(256) void mfma_gemm_kernel(const float* __restrict__ A,
                                                        const short* __restrict__ Bt,
                                                        float* __restrict__ Cacc,
                                                        int K, int chunk) {
    __shared__ __align__(16) short As[64 * 40];
    __shared__ __align__(16) short Bs[128 * 40];
    int tid = threadIdx.x;
    int w = tid >> 6;          // wave 0..3
    int lane = tid & 63;
    int m16 = lane & 15;
    int kq = lane >> 4;
    int bm = blockIdx.x;
    int kbeg = blockIdx.y * chunk;

    f32x4 acc[8];
#pragma unroll
    for (int i = 0; i < 8; i++) acc[i] = (f32x4){0.f, 0.f, 0.f, 0.f};

    const float* Ab = A + (size_t)bm * 64 * K;
    int arow = tid >> 2, akg = (tid & 3) * 8;

    for (int k0 = kbeg; k0 < kbeg + chunk; k0 += 32) {
        // stage A: 64x32 fp32 -> bf16
        {
            const float* src = Ab + (size_t)arow * K + k0 + akg;
            float4 v0 = *(const float4*)src;
            float4 v1 = *(const float4*)(src + 4);
            short8 t;
            t[0] = f2bf(v0.x); t[1] = f2bf(v0.y); t[2] = f2bf(v0.z); t[3] = f2bf(v0.w);
            t[4] = f2bf(v1.x); t[5] = f2bf(v1.y); t[6] = f2bf(v1.z); t[7] = f2bf(v1.w);
            *(short8*)&As[arow * 40 + akg] = t;
        }
        // stage B: 128x32 bf16 (Bt rows are columns of B)
        for (int l = tid; l < 512; l += 256) {
            int nn = l >> 2, kg = (l & 3) * 8;
            *(short8*)&Bs[nn * 40 + kg] = *(const short8*)&Bt[(size_t)nn * K + k0 + kg];
        }
        __syncthreads();
        short8 a = *(short8*)&As[(w * 16 + m16) * 40 + kq * 8];
#pragma unroll
        for (int nf = 0; nf < 8; nf++) {
            short8 b = *(short8*)&Bs[(nf * 16 + m16) * 40 + kq * 8];
            acc[nf] = __builtin_amdgcn_mfma_f32_16x16x32_bf16(a, b, acc[nf], 0, 0, 0);
        }
        __syncthreads();
    }
    int rbase = bm * 64 + w * 16 + kq * 4;
#pragma unroll
    for (int nf = 0; nf < 8; nf++) {
        int col = nf * 16 + m16;
#pragma unroll
        for (int i = 0; i < 4; i++)
            atomicAdd(&Cacc[(size_t)(rbase + i) * 128 + col], acc[nf][i]);
    }
}

// ---------------- relu: dst = max(acc, 0) ----------------
__global__ void relu_kernel(const float* __restrict__ a, float* __restrict__ d, int count) {
    int i = blockIdx.x * blockDim.x + threadIdx.x;
    if (i < count) { float v = a[i]; d[i] = v > 0.f ? v : 0.f; }
}

// ---------------- u = src (copy) ----------------
__global__ void copy_kernel(const float* __restrict__ src, float* __restrict__ dst, int count) {
    int idx = blockIdx.x * blockDim.x + threadIdx.x;
    if (idx < count) dst[idx] = src[idx];
}

// ---------------- u[perm[j]] += xc[j] ----------------
__global__ void scatter_add_kernel(const float* __restrict__ xc, const int* __restrict__ perm,
                                   float* __restrict__ u, int k) {
    int idx = blockIdx.x * blockDim.x + threadIdx.x;
    if (idx >= k * D) return;
    int j = idx >> 7;
    int d = idx & 127;
    u[(size_t)perm[j] * D + d] += xc[idx];
}

extern "C" void kernel_launch(void* const* d_in, const int* in_sizes, int n_in,
                              void* d_out, int out_size, void* d_ws, size_t ws_size,
                              hipStream_t stream) {
    const float* feat = (const float*)d_in[0];
    const float* H    = (const float*)d_in[1];
    const float* p_w[3]  = {(const float*)d_in[2], (const float*)d_in[3], (const float*)d_in[4]};
    const float* Wd[3]   = {(const float*)d_in[5], (const float*)d_in[7], (const float*)d_in[9]};
    const float* bd[3]   = {(const float*)d_in[6], (const float*)d_in[8], (const float*)d_in[10]};
    const float* Wu[3]   = {(const float*)d_in[11], (const float*)d_in[13], (const float*)d_in[15]};
    const float* bu[3]   = {(const float*)d_in[12], (const float*)d_in[14], (const float*)d_in[16]};
    float* out = (float*)d_out;

    // ---- workspace carving ----
    char* w = (char*)d_ws;
    size_t off = 0;
    auto alloc = [&](size_t nbytes) { void* p = w + off; off += (nbytes + 255) & ~255ull; return p; };
    float* Hg0 = (float*)alloc(4096ull * 4096 * 4);
    float* Hg1 = (float*)alloc(2048ull * 2048 * 4);
    float* Hg2 = (float*)alloc(1024ull * 1024 * 4);
    float* x1  = (float*)alloc(4096ull * D * 4);
    float* x2  = (float*)alloc(2048ull * D * 4);
    float* xp  = (float*)alloc(4096ull * D * 4);   // down: pooled x; up: aliased as Tt (bf16 128x8192)
    float* tbuf = (float*)alloc(8192ull * D * 4);
    float* ubuf = (float*)alloc(8192ull * D * 4);  // up input; also aliased as gemm accumulator
    float* xc  = (float*)alloc(4096ull * D * 4);
    float* score = (float*)alloc(8192 * 4);
    float* gate  = (float*)alloc(4096 * 4);
    int* perm0 = (int*)alloc(4096 * 4);
    int* perm1 = (int*)alloc(2048 * 4);
    int* perm2 = (int*)alloc(1024 * 4);
    float* abuf = ubuf;          // fp32 accumulator for split-K gemms (safe: ubuf dead by then)
    short* ttb  = (short*)xp;    // bf16 transposed T (up path only; xp dead in up path)

    const int ks[3] = {4096, 2048, 1024};
    const int ns[3] = {8192, 4096, 2048};
    int* perms[3] = {perm0, perm1, perm2};
    float* Hgs[3] = {Hg0, Hg1, Hg2};
    const float* xin[3] = {feat, x1, x2};
    float* xout[3] = {x1, x2, xc};
    const int dS[3] = {8, 8, 16};   // split-K factors, down

    // ---------------- down path (fp32) ----------------
    for (int i = 0; i < 3; i++) {
        int n = ns[i], k = ks[i];
        int lg = (k == 4096) ? 12 : (k == 2048 ? 11 : 10);
        score_kernel<<<n, 128, 0, stream>>>(xin[i], p_w[i], score, n);
        topk_sort_kernel<<<1, 1024, n * 8, stream>>>(score, n, k, perms[i], gate);
        pool_gather_kernel<<<(k * D) / 256, 256, 0, stream>>>(xin[i], perms[i], gate, xp, k);
        h_gather_kernel<<<(k * k) / 256, 256, 0, stream>>>(H, perms[i], Hgs[i], k, lg);
        gemm_xw_kernel<<<k / 64, 256, 0, stream>>>(xp, Wd[i], bd[i], tbuf, k);
        hipMemsetAsync(abuf, 0, (size_t)k * D * 4, stream);
        dim3 g(k / 64, dS[i]);
        gemm_f32_kernel<<<g, 256, 0, stream>>>(Hgs[i], tbuf, abuf, k, k / dS[i]);
        relu_kernel<<<(k * D) / 256, 256, 0, stream>>>(abuf, xout[i], k * D);
    }

    // ---------------- up path (bf16 MFMA) ----------------
    const float* res[3] = {x2, x1, feat};
    const float* graphs[3] = {Hg1, Hg0, H};
    int* uperm[3] = {perm2, perm1, perm0};
    const int un[3] = {2048, 4096, 8192};
    const int uk[3] = {1024, 2048, 4096};
    const int uS[3] = {8, 8, 4};
    for (int i = 0; i < 3; i++) {
        int n = un[i], k = uk[i];
        copy_kernel<<<(n * D) / 256, 256, 0, stream>>>(res[i], ubuf, n * D);
        scatter_add_kernel<<<(k * D) / 256, 256, 0, stream>>>(xc, uperm[i], ubuf, k);
        gemm_xw_kernel<<<n / 64, 256, 0, stream>>>(ubuf, Wu[i], bu[i], tbuf, n);
        dim3 tg(n / 32, 4);
        transpose_cvt_kernel<<<tg, 256, 0, stream>>>(tbuf, ttb, n);
        hipMemsetAsync(abuf, 0, (size_t)n * D * 4, stream);
        dim3 g(n / 64, uS[i]);
        mfma_gemm_kernel<<<g, 256, 0, stream>>>(graphs[i], ttb, abuf, n, n / uS[i]);
        float* dst = (i == 2) ? out : xc;
        relu_kernel<<<(n * D) / 256, 256, 0, stream>>>(abuf, dst, n * D);
    }
    (void)in_sizes; (void)n_in; (void)out_size; (void)ws_size;
}

// Round 3
// 1002.562 us; speedup vs baseline: 3.1097x; 1.3657x over previous
//
#include <hip/hip_runtime.h>
#include <math.h>

#define N0 8192
#define D 128

typedef __attribute__((ext_vector_type(8))) short short8;
typedef __attribute__((ext_vector_type(4))) float f32x4;

__device__ inline short f2bf(float f) {
    unsigned u = __float_as_uint(f);
    u = u + 0x7fffu + ((u >> 16) & 1u);
    return (short)(u >> 16);
}

// RNE 3-way bf16 split: v ~= h + m + l, residual ~2^-24 relative
__device__ inline void split3(float v, short& h, short& m, short& l) {
    unsigned u = __float_as_uint(v);
    unsigned hs = (u + 0x7fffu + ((u >> 16) & 1u)) >> 16;
    h = (short)hs;
    float rem = v - __uint_as_float(hs << 16);     // exact
    unsigned ur = __float_as_uint(rem);
    unsigned ms = (ur + 0x7fffu + ((ur >> 16) & 1u)) >> 16;
    m = (short)ms;
    float rem2 = rem - __uint_as_float(ms << 16);  // exact
    unsigned u2 = __float_as_uint(rem2);
    l = (short)((u2 + 0x7fffu + ((u2 >> 16) & 1u)) >> 16);
}

// ---------------- score: s[i] = tanh((x[i]·w)/||w||), tanh in fp64 ----------------
__global__ void score_kernel(const float* __restrict__ x, const float* __restrict__ w,
                             float* __restrict__ score, int n) {
    __shared__ float red[128];
    __shared__ float red2[128];
    int row = blockIdx.x;
    int t = threadIdx.x;
    float wv = w[t];
    float xv = x[row * D + t];
    red[t] = xv * wv;
    red2[t] = wv * wv;
    __syncthreads();
    for (int s = 64; s > 0; s >>= 1) {
        if (t < s) { red[t] += red[t + s]; red2[t] += red2[t + s]; }
        __syncthreads();
    }
    if (t == 0) {
        double a = (double)red[0] / sqrt((double)red2[0]);
        score[row] = (float)tanh(a);
    }
}

// ---------------- exact top-k: bitonic sort of (desc score, asc index) keys -------
__global__ void topk_sort_kernel(const float* __restrict__ score, int n, int k,
                                 int* __restrict__ perm, float* __restrict__ gate) {
    extern __shared__ unsigned long long keys[];
    int t = threadIdx.x;
    int bs = blockDim.x;
    for (int i = t; i < n; i += bs) {
        unsigned int b = __float_as_uint(score[i]);
        unsigned int ord = (b & 0x80000000u) ? ~b : (b | 0x80000000u);
        unsigned int inv = ~ord;
        keys[i] = ((unsigned long long)inv << 32) | (unsigned int)i;
    }
    __syncthreads();
    for (int len = 2; len <= n; len <<= 1) {
        for (int str = len >> 1; str > 0; str >>= 1) {
            for (int i = t; i < n; i += bs) {
                int j = i ^ str;
                if (j > i) {
                    unsigned long long a = keys[i], c = keys[j];
                    bool up = ((i & len) == 0);
                    if ((a > c) == up) { keys[i] = c; keys[j] = a; }
                }
            }
            __syncthreads();
        }
    }
    for (int i = t; i < k; i += bs) {
        int idx = (int)(keys[i] & 0xffffffffu);
        perm[i] = idx;
        gate[i] = score[idx];
    }
}

// ---------------- xp[j] = x[perm[j]] * gate[j] ----------------
__global__ void pool_gather_kernel(const float* __restrict__ x, const int* __restrict__ perm,
                                   const float* __restrict__ gate, float* __restrict__ xp, int k) {
    int idx = blockIdx.x * blockDim.x + threadIdx.x;
    if (idx >= k * D) return;
    int j = idx >> 7;
    int d = idx & 127;
    xp[idx] = x[perm[j] * D + d] * gate[j];
}

// ---------------- Hg[r][c] = H[perm[r]][perm[c]] ----------
__global__ void h_gather_kernel(const float* __restrict__ H, const int* __restrict__ perm,
                                float* __restrict__ Hg, int k, int lg) {
    int idx = blockIdx.x * blockDim.x + threadIdx.x;
    int r = idx >> lg;
    int c = idx & (k - 1);
    if (r >= k) return;
    Hg[idx] = H[(size_t)perm[r] * N0 + perm[c]];
}

// ------- single-plane transpose+convert: Tt(128 x n) = bf16(T(n x 128))^T -------
__global__ void transpose_cvt_kernel(const float* __restrict__ T, short* __restrict__ Tt, int n) {
    __shared__ float tile[32][33];
    int tx = threadIdx.x & 31, ty = threadIdx.x >> 5;
    int r0 = blockIdx.x * 32, c0 = blockIdx.y * 32;
#pragma unroll
    for (int k = 0; k < 4; k++)
        tile[ty + k * 8][tx] = T[(size_t)(r0 + ty + k * 8) * 128 + c0 + tx];
    __syncthreads();
#pragma unroll
    for (int k = 0; k < 4; k++)
        Tt[(size_t)(c0 + ty + k * 8) * n + r0 + tx] = f2bf(tile[tx][ty + k * 8]);
}

// ------- split transpose: 3 bf16 planes (128 x n) from T(n x 128 fp32) -------
__global__ void split_transpose_kernel(const float* __restrict__ T, short* __restrict__ Th,
                                       short* __restrict__ Tm, short* __restrict__ Tl, int n) {
    __shared__ float tile[32][33];
    int tx = threadIdx.x & 31, ty = threadIdx.x >> 5;
    int r0 = blockIdx.x * 32, c0 = blockIdx.y * 32;
#pragma unroll
    for (int k = 0; k < 4; k++)
        tile[ty + k * 8][tx] = T[(size_t)(r0 + ty + k * 8) * 128 + c0 + tx];
    __syncthreads();
#pragma unroll
    for (int k = 0; k < 4; k++) {
        float v = tile[tx][ty + k * 8];
        short h, m, l;
        split3(v, h, m, l);
        size_t o = (size_t)(c0 + ty + k * 8) * n + r0 + tx;
        Th[o] = h; Tm[o] = m; Tl[o] = l;
    }
}

// ------- fp32-accurate MFMA gemm via 3-way bf16 split, 6 products -------
// A: M x K fp32 (split in-kernel). Bh/Bm/Bl: 128 x K bf16 planes (pre-split, transposed).
// Writes partial slice blockIdx.y of pbuf (slices of M x 128 fp32).
__global__ __launch_bounds__(256) void mfma_split6_kernel(
        const float* __restrict__ A, const short* __restrict__ Bh,
        const short* __restrict__ Bm, const short* __restrict__ Bl,
        float* __restrict__ pbuf, int M, int K, int chunk) {
    __shared__ __align__(16) short Ah[64 * 40], Am[64 * 40], Al[64 * 40];
    __shared__ __align__(16) short Bhs[128 * 40], Bms[128 * 40], Bls[128 * 40];
    int tid = threadIdx.x;
    int w = tid >> 6, lane = tid & 63;
    int m16 = lane & 15, kq = lane >> 4;
    int bm = blockIdx.x;
    int kbeg = blockIdx.y * chunk;

    f32x4 acc[8];
#pragma unroll
    for (int i = 0; i < 8; i++) acc[i] = (f32x4){0.f, 0.f, 0.f, 0.f};

    const float* Ab = A + (size_t)bm * 64 * K;
    int arow = tid >> 2, acg = (tid & 3) * 8;

    for (int k0 = kbeg; k0 < kbeg + chunk; k0 += 32) {
        // stage + split A: 64 x 32 fp32 -> 3 bf16 planes
        {
            const float* src = Ab + (size_t)arow * K + k0 + acg;
            float4 v0 = *(const float4*)src;
            float4 v1 = *(const float4*)(src + 4);
            float vv[8] = {v0.x, v0.y, v0.z, v0.w, v1.x, v1.y, v1.z, v1.w};
            short8 th, tm, tl;
#pragma unroll
            for (int j = 0; j < 8; j++) { short h, m, l; split3(vv[j], h, m, l); th[j] = h; tm[j] = m; tl[j] = l; }
            *(short8*)&Ah[arow * 40 + acg] = th;
            *(short8*)&Am[arow * 40 + acg] = tm;
            *(short8*)&Al[arow * 40 + acg] = tl;
        }
        // stage B planes: 128 x 32 bf16 each
        for (int l = tid; l < 512; l += 256) {
            int nn = l >> 2, kg = (l & 3) * 8;
            size_t go = (size_t)nn * K + k0 + kg;
            int lo = nn * 40 + kg;
            *(short8*)&Bhs[lo] = *(const short8*)&Bh[go];
            *(short8*)&Bms[lo] = *(const short8*)&Bm[go];
            *(short8*)&Bls[lo] = *(const short8*)&Bl[go];
        }
        __syncthreads();
        int ao = (w * 16 + m16) * 40 + kq * 8;
        short8 a_h = *(short8*)&Ah[ao];
        short8 a_m = *(short8*)&Am[ao];
        short8 a_l = *(short8*)&Al[ao];
#pragma unroll
        for (int nf = 0; nf < 8; nf++) {
            int bo = (nf * 16 + m16) * 40 + kq * 8;
            short8 b_h = *(short8*)&Bhs[bo];
            short8 b_m = *(short8*)&Bms[bo];
            short8 b_l = *(short8*)&Bls[bo];
            acc[nf] = __builtin_amdgcn_mfma_f32_16x16x32_bf16(a_h, b_h, acc[nf], 0, 0, 0);
            acc[nf] = __builtin_amdgcn_mfma_f32_16x16x32_bf16(a_h, b_m, acc[nf], 0, 0, 0);
            acc[nf] = __builtin_amdgcn_mfma_f32_16x16x32_bf16(a_m, b_h, acc[nf], 0, 0, 0);
            acc[nf] = __builtin_amdgcn_mfma_f32_16x16x32_bf16(a_h, b_l, acc[nf], 0, 0, 0);
            acc[nf] = __builtin_amdgcn_mfma_f32_16x16x32_bf16(a_l, b_h, acc[nf], 0, 0, 0);
            acc[nf] = __builtin_amdgcn_mfma_f32_16x16x32_bf16(a_m, b_m, acc[nf], 0, 0, 0);
        }
        __syncthreads();
    }
    float* pb = pbuf + (size_t)blockIdx.y * M * 128;
    int rbase = bm * 64 + w * 16 + kq * 4;
#pragma unroll
    for (int nf = 0; nf < 8; nf++) {
        int col = nf * 16 + m16;
#pragma unroll
        for (int i = 0; i < 4; i++)
            pb[(size_t)(rbase + i) * 128 + col] = acc[nf][i];
    }
}

// ------- bf16 MFMA gemm (1 product): A fp32 M x K (cvt in-kernel), Bt 128 x K bf16 -------
__global__ __launch_bounds__(256) void mfma_gemm1_kernel(
        const float* __restrict__ A, const short* __restrict__ Bt,
        float* __restrict__ pbuf, int M, int K, int chunk) {
    __shared__ __align__(16) short As[64 * 40];
    __shared__ __align__(16) short Bs[128 * 40];
    int tid = threadIdx.x;
    int w = tid >> 6, lane = tid & 63;
    int m16 = lane & 15, kq = lane >> 4;
    int bm = blockIdx.x;
    int kbeg = blockIdx.y * chunk;

    f32x4 acc[8];
#pragma unroll
    for (int i = 0; i < 8; i++) acc[i] = (f32x4){0.f, 0.f, 0.f, 0.f};

    const float* Ab = A + (size_t)bm * 64 * K;
    int arow = tid >> 2, acg = (tid & 3) * 8;

    for (int k0 = kbeg; k0 < kbeg + chunk; k0 += 32) {
        {
            const float* src = Ab + (size_t)arow * K + k0 + acg;
            float4 v0 = *(const float4*)src;
            float4 v1 = *(const float4*)(src + 4);
            short8 t;
            t[0] = f2bf(v0.x); t[1] = f2bf(v0.y); t[2] = f2bf(v0.z); t[3] = f2bf(v0.w);
            t[4] = f2bf(v1.x); t[5] = f2bf(v1.y); t[6] = f2bf(v1.z); t[7] = f2bf(v1.w);
            *(short8*)&As[arow * 40 + acg] = t;
        }
        for (int l = tid; l < 512; l += 256) {
            int nn = l >> 2, kg = (l & 3) * 8;
            *(short8*)&Bs[nn * 40 + kg] = *(const short8*)&Bt[(size_t)nn * K + k0 + kg];
        }
        __syncthreads();
        short8 a = *(short8*)&As[(w * 16 + m16) * 40 + kq * 8];
#pragma unroll
        for (int nf = 0; nf < 8; nf++) {
            short8 b = *(short8*)&Bs[(nf * 16 + m16) * 40 + kq * 8];
            acc[nf] = __builtin_amdgcn_mfma_f32_16x16x32_bf16(a, b, acc[nf], 0, 0, 0);
        }
        __syncthreads();
    }
    float* pb = pbuf + (size_t)blockIdx.y * M * 128;
    int rbase = bm * 64 + w * 16 + kq * 4;
#pragma unroll
    for (int nf = 0; nf < 8; nf++) {
        int col = nf * 16 + m16;
#pragma unroll
        for (int i = 0; i < 4; i++)
            pb[(size_t)(rbase + i) * 128 + col] = acc[nf][i];
    }
}

// ------- reduce split-K partials + optional bias + optional relu -------
__global__ void reduce_kernel(const float* __restrict__ pbuf, int S, size_t MC,
                              const float* __restrict__ bias, int relu,
                              float* __restrict__ dst) {
    size_t idx = ((size_t)blockIdx.x * 256 + threadIdx.x) * 4;
    if (idx >= MC) return;
    float4 v = *(const float4*)(pbuf + idx);
    for (int s = 1; s < S; s++) {
        float4 t = *(const float4*)(pbuf + (size_t)s * MC + idx);
        v.x += t.x; v.y += t.y; v.z += t.z; v.w += t.w;
    }
    if (bias) {
        int c = (int)(idx & 127);
        v.x += bias[c]; v.y += bias[c + 1]; v.z += bias[c + 2]; v.w += bias[c + 3];
    }
    if (relu) {
        v.x = v.x > 0.f ? v.x : 0.f; v.y = v.y > 0.f ? v.y : 0.f;
        v.z = v.z > 0.f ? v.z : 0.f; v.w = v.w > 0.f ? v.w : 0.f;
    }
    *(float4*)(dst + idx) = v;
}

// ---------------- u = src (copy) ----------------
__global__ void copy_kernel(const float* __restrict__ src, float* __restrict__ dst, int count) {
    int idx = blockIdx.x * blockDim.x + threadIdx.x;
    if (idx < count) dst[idx] = src[idx];
}

// ---------------- u[perm[j]] += xc[j] ----------------
__global__ void scatter_add_kernel(const float* __restrict__ xc, const int* __restrict__ perm,
                                   float* __restrict__ u, int k) {
    int idx = blockIdx.x * blockDim.x + threadIdx.x;
    if (idx >= k * D) return;
    int j = idx >> 7;
    int d = idx & 127;
    u[(size_t)perm[j] * D + d] += xc[idx];
}

extern "C" void kernel_launch(void* const* d_in, const int* in_sizes, int n_in,
                              void* d_out, int out_size, void* d_ws, size_t ws_size,
                              hipStream_t stream) {
    const float* feat = (const float*)d_in[0];
    const float* H    = (const float*)d_in[1];
    const float* p_w[3]  = {(const float*)d_in[2], (const float*)d_in[3], (const float*)d_in[4]};
    const float* Wd[3]   = {(const float*)d_in[5], (const float*)d_in[7], (const float*)d_in[9]};
    const float* bd[3]   = {(const float*)d_in[6], (const float*)d_in[8], (const float*)d_in[10]};
    const float* Wu[3]   = {(const float*)d_in[11], (const float*)d_in[13], (const float*)d_in[15]};
    const float* bu[3]   = {(const float*)d_in[12], (const float*)d_in[14], (const float*)d_in[16]};
    float* out = (float*)d_out;

    // ---- workspace carving ----
    char* wsp = (char*)d_ws;
    size_t off = 0;
    auto alloc = [&](size_t nbytes) { void* p = wsp + off; off += (nbytes + 255) & ~255ull; return p; };
    float* Hg0 = (float*)alloc(4096ull * 4096 * 4);
    float* Hg1 = (float*)alloc(2048ull * 2048 * 4);
    float* Hg2 = (float*)alloc(1024ull * 1024 * 4);
    float* x1  = (float*)alloc(4096ull * D * 4);
    float* x2  = (float*)alloc(2048ull * D * 4);
    float* xp  = (float*)alloc(4096ull * D * 4);   // down: pooled x; up: aliased as ttb (bf16 128x8192)
    float* tbuf = (float*)alloc(8192ull * D * 4);
    float* ubuf = (float*)alloc(8192ull * D * 4);
    float* xc  = (float*)alloc(4096ull * D * 4);
    float* pbuf = (float*)alloc(8ull * 4096 * 128 * 4);   // split-K partial slices (16.8 MB)
    short* Bth = (short*)alloc(128ull * 4096 * 2);
    short* Btm = (short*)alloc(128ull * 4096 * 2);
    short* Btl = (short*)alloc(128ull * 4096 * 2);
    short* Wth = (short*)alloc(128ull * 128 * 2);
    short* Wtm = (short*)alloc(128ull * 128 * 2);
    short* Wtl = (short*)alloc(128ull * 128 * 2);
    float* score = (float*)alloc(8192 * 4);
    float* gate  = (float*)alloc(4096 * 4);
    int* perm0 = (int*)alloc(4096 * 4);
    int* perm1 = (int*)alloc(2048 * 4);
    int* perm2 = (int*)alloc(1024 * 4);
    short* ttb = (short*)xp;

    const int ks[3] = {4096, 2048, 1024};
    const int ns[3] = {8192, 4096, 2048};
    int* perms[3] = {perm0, perm1, perm2};
    float* Hgs[3] = {Hg0, Hg1, Hg2};
    const float* xin[3] = {feat, x1, x2};
    float* xout[3] = {x1, x2, xc};
    const int dS[3] = {8, 8, 16};

    // ---------------- down path (fp32-accurate split6 MFMA) ----------------
    for (int i = 0; i < 3; i++) {
        int n = ns[i], k = ks[i];
        int lg = (k == 4096) ? 12 : (k == 2048 ? 11 : 10);
        score_kernel<<<n, 128, 0, stream>>>(xin[i], p_w[i], score, n);
        topk_sort_kernel<<<1, 1024, n * 8, stream>>>(score, n, k, perms[i], gate);
        pool_gather_kernel<<<(k * D) / 256, 256, 0, stream>>>(xin[i], perms[i], gate, xp, k);
        h_gather_kernel<<<(k * k) / 256, 256, 0, stream>>>(H, perms[i], Hgs[i], k, lg);
        // T = xp @ Wd + bd   (split6, K=128, S=2)
        dim3 wg(4, 4);
        split_transpose_kernel<<<wg, 256, 0, stream>>>(Wd[i], Wth, Wtm, Wtl, 128);
        dim3 g1(k / 64, 2);
        mfma_split6_kernel<<<g1, 256, 0, stream>>>(xp, Wth, Wtm, Wtl, pbuf, k, 128, 64);
        reduce_kernel<<<(k * 128 / 4 + 255) / 256, 256, 0, stream>>>(pbuf, 2, (size_t)k * 128, bd[i], 0, tbuf);
        // xout = relu(Hg @ T)  (split6, K=k, S=dS[i])
        dim3 tg(k / 32, 4);
        split_transpose_kernel<<<tg, 256, 0, stream>>>(tbuf, Bth, Btm, Btl, k);
        dim3 g2(k / 64, dS[i]);
        mfma_split6_kernel<<<g2, 256, 0, stream>>>(Hgs[i], Bth, Btm, Btl, pbuf, k, k, k / dS[i]);
        reduce_kernel<<<(k * 128 / 4 + 255) / 256, 256, 0, stream>>>(pbuf, dS[i], (size_t)k * 128, nullptr, 1, xout[i]);
    }

    // ---------------- up path (bf16 MFMA) ----------------
    const float* res[3] = {x2, x1, feat};
    const float* graphs[3] = {Hg1, Hg0, H};
    int* uperm[3] = {perm2, perm1, perm0};
    const int un[3] = {2048, 4096, 8192};
    const int uk[3] = {1024, 2048, 4096};
    const int uS[3] = {8, 8, 4};
    for (int i = 0; i < 3; i++) {
        int n = un[i], k = uk[i];
        copy_kernel<<<(n * D) / 256, 256, 0, stream>>>(res[i], ubuf, n * D);
        scatter_add_kernel<<<(k * D) / 256, 256, 0, stream>>>(xc, uperm[i], ubuf, k);
        // T = ubuf @ Wu + bu  (bf16, K=128, S=2)
        dim3 wg(4, 4);
        transpose_cvt_kernel<<<wg, 256, 0, stream>>>(Wu[i], Wth, 128);
        dim3 g1(n / 64, 2);
        mfma_gemm1_kernel<<<g1, 256, 0, stream>>>(ubuf, Wth, pbuf, n, 128, 64);
        reduce_kernel<<<(n * 128 / 4 + 255) / 256, 256, 0, stream>>>(pbuf, 2, (size_t)n * 128, bu[i], 0, tbuf);
        // dst = relu(graph @ T)  (bf16, K=n, S=uS[i])
        dim3 tg(n / 32, 4);
        transpose_cvt_kernel<<<tg, 256, 0, stream>>>(tbuf, ttb, n);
        dim3 g2(n / 64, uS[i]);
        mfma_gemm1_kernel<<<g2, 256, 0, stream>>>(graphs[i], ttb, pbuf, n, n, n / uS[i]);
        float* dst = (i == 2) ? out : xc;
        reduce_kernel<<<(n * 128 / 4 + 255) / 256, 256, 0, stream>>>(pbuf, uS[i], (size_t)n * 128, nullptr, 1, dst);
    }
    (void)in_sizes; (void)n_in; (void)out_size; (void)ws_size;
}